// Round 8
// baseline (82.001 us; speedup 1.0000x reference)
//
#include <hip/hip_runtime.h>
#include <math.h>

#define KP   125        // 5*5*5 filter taps
#define PADE 732        // 9*9*9 = 729 pair-entries (dwords), rounded to /4
#define FPB  4          // one wave per filter, 4 filters per 256-thread block

typedef _Float16 half_t;
typedef half_t h2 __attribute__((ext_vector_type(2)));
typedef __fp16 fp16x2 __attribute__((ext_vector_type(2)));

static __device__ __forceinline__ h2 h2fma(h2 a, h2 b, h2 c) {
    return __builtin_elementwise_fma(a, b, c);
}
static __device__ __forceinline__ h2 cvt_pk(float a, float b) {
    fp16x2 t = __builtin_amdgcn_cvt_pkrtz(a, b);   // v_cvt_pkrtz_f16_f32
    return __builtin_bit_cast(h2, t);
}

// ---------- Kernel A: per-filter Rodrigues -> Rws[n*12 + 0..8] ----------
__global__ __launch_bounds__(256) void rodrigues_kernel(
    const float* __restrict__ theta_v,  // N*3
    const float* __restrict__ theta,    // N
    float* __restrict__ Rws, int N)
{
    const int n = blockIdx.x * 256 + threadIdx.x;
    if (n >= N) return;
    const float ax = theta_v[n * 3 + 0];
    const float ay = theta_v[n * 3 + 1];
    const float az = theta_v[n * 3 + 2];
    const float th = theta[n];
    const float d2  = ax * ax + ay * ay + az * az;
    const float inv = rsqrtf(fmaxf(d2, 1e-24f));
    const float vx = ax * inv, vy = ay * inv, vz = az * inv;
    float s, cth;
    __sincosf(th, &s, &cth);
    const float c = 1.0f - cth;
    float4 r0, r1, r2;
    r0.x = 1.0f - c * (vy * vy + vz * vz);   // R00
    r0.y = -s * vz + c * (vx * vy);          // R01
    r0.z =  s * vy + c * (vx * vz);          // R02
    r0.w =  s * vz + c * (vx * vy);          // R10
    r1.x = 1.0f - c * (vx * vx + vz * vz);   // R11
    r1.y = -s * vx + c * (vy * vz);          // R12
    r1.z = -s * vy + c * (vx * vz);          // R20
    r1.w =  s * vx + c * (vy * vz);          // R21
    r2.x = 1.0f - c * (vx * vx + vy * vy);   // R22
    r2.y = 0.f; r2.z = 0.f; r2.w = 0.f;
    float4* o = (float4*)(Rws + (long long)n * 12);
    o[0] = r0; o[1] = r1; o[2] = r2;
}

// ---------- Kernel B: barrier-free fp16-pair sample kernel ----------
__global__ __launch_bounds__(FPB * 64) void fastrot_kernel(
    const float* __restrict__ vol,      // N*125
    const float* __restrict__ Rws,      // N*12
    float* __restrict__ out)            // N*125
{
    // pad entries: uint dword = half2 {f(z,y,x), f(z,y,x+1)}, 9^3 frame,
    // interior (5^3 data) at +2 in each axis.
    __shared__ __align__(16) unsigned int pad[FPB][PADE];

    const int lane = threadIdx.x & 63;
    const int wvu = __builtin_amdgcn_readfirstlane(threadIdx.x >> 6);
    const int n   = blockIdx.x * FPB + wvu;

    // ---- zero-fill 9^3 pair frame: 183 uint4 per filter ----
    uint4* p4 = (uint4*)(&pad[wvu][0]);
    const uint4 z4 = make_uint4(0u, 0u, 0u, 0u);
    p4[lane]      = z4;
    p4[lane + 64] = z4;
    if (lane < (PADE / 4 - 128)) p4[lane + 128] = z4;   // 183 total

    // ---- load filter values + x-neighbors (coalesced / L1 hits) ----
    const float* vn = vol + (long long)n * KP;
    const int p0 = lane, p1 = lane + 64;

    const int i0 = (p0 * 41) >> 10;
    const int q0 = (p0 * 205) >> 10;
    const int j0 = q0 - i0 * 5;
    const int l0 = p0 - q0 * 5;
    const int i1 = (p1 * 41) >> 10;
    const int q1 = (p1 * 205) >> 10;
    const int j1 = q1 - i1 * 5;
    const int l1 = p1 - q1 * 5;

    const float fv0 = vn[p0];
    const float fv1 = (p1 < KP) ? vn[p1] : 0.0f;
    const float nx0 = (l0 < 4) ? vn[p0 + 1] : 0.0f;                 // p0+1 <= 64
    const float nx1 = (l1 < 4 && p1 < KP) ? vn[p1 + 1] : 0.0f;      // <= 124

    // ---- R for this wave's filter (wave-uniform scalar loads) ----
    const float* Rp = Rws + (long long)n * 12;
    const float R00 = Rp[0], R01 = Rp[1], R02 = Rp[2];
    const float R10 = Rp[3], R11 = Rp[4], R12 = Rp[5];
    const float R20 = Rp[6], R21 = Rp[7], R22 = Rp[8];

    // ---- scatter pair entries: e = (i+2)*81 + (j+2)*9 + (l+2) ----
    {
        const h2 pk0 = cvt_pk(fv0, nx0);
        const int e0 = i0 * 81 + j0 * 9 + l0 + 182;
        pad[wvu][e0] = __builtin_bit_cast(unsigned int, pk0);
        if (l0 == 0) {   // left-border entry {0, v}
            const h2 pb = cvt_pk(0.0f, fv0);
            pad[wvu][e0 - 1] = __builtin_bit_cast(unsigned int, pb);
        }
        if (p1 < KP) {
            const h2 pk1 = cvt_pk(fv1, nx1);
            const int e1 = i1 * 81 + j1 * 9 + l1 + 182;
            pad[wvu][e1] = __builtin_bit_cast(unsigned int, pk1);
            if (l1 == 0) {
                const h2 pb = cvt_pk(0.0f, fv1);
                pad[wvu][e1 - 1] = __builtin_bit_cast(unsigned int, pb);
            }
        }
    }

    const unsigned int* pwu = &pad[wvu][0];
    float* on = out + (long long)n * KP;

    // frame coord: xs = (gx+1)*2 + 2, folded const = +4; xs in [0.53, 7.47]
    // -> trunc == floor, x0 in [0,7], reads x0+1 <= 8: exact zero-pad, no clamps.
    auto sample = [&](float Bi, float Bj, float Bl) -> float {
        const float xs = fmaf(Bi, R00, fmaf(Bj, R10, fmaf(Bl, R20, 4.0f)));
        const float ys = fmaf(Bi, R01, fmaf(Bj, R11, fmaf(Bl, R21, 4.0f)));
        const float zs = fmaf(Bi, R02, fmaf(Bj, R12, fmaf(Bl, R22, 4.0f)));
        const int x0 = (int)xs, y0 = (int)ys, z0 = (int)zs;
        const float wx = __builtin_amdgcn_fractf(xs);
        const float wy = __builtin_amdgcn_fractf(ys);
        const float wz = __builtin_amdgcn_fractf(zs);
        const int ci = z0 * 81 + y0 * 9 + x0;        // in [0, 637]

        // 2x ds_read2_b32: (ci, ci+81) and (ci+9, ci+90)
        const unsigned int A0 = pwu[ci];        // {a00,a01} z0,y0
        const unsigned int A1 = pwu[ci + 81];   // {a20,a21} z1,y0
        const unsigned int B0 = pwu[ci + 9];    // {a10,a11} z0,y1
        const unsigned int B1 = pwu[ci + 90];   // {a30,a31} z1,y1

        // repack to {lo,lo} / {hi,hi} across the z-pair: v_perm_b32
        const unsigned int c0u = __builtin_amdgcn_perm(A1, A0, 0x05040100u); // {a00,a20}
        const unsigned int c1u = __builtin_amdgcn_perm(A1, A0, 0x07060302u); // {a01,a21}
        const unsigned int d0u = __builtin_amdgcn_perm(B1, B0, 0x05040100u); // {a10,a30}
        const unsigned int d1u = __builtin_amdgcn_perm(B1, B0, 0x07060302u); // {a11,a31}
        const h2 C0 = __builtin_bit_cast(h2, c0u);
        const h2 C1 = __builtin_bit_cast(h2, c1u);
        const h2 D0 = __builtin_bit_cast(h2, d0u);
        const h2 D1 = __builtin_bit_cast(h2, d1u);

        const h2 wxh = cvt_pk(wx, wx);
        const h2 wyh = cvt_pk(wy, wy);

        const h2 r02 = h2fma(wxh, C1 - C0, C0);   // {r0(z0,y0), r2(z1,y0)}
        const h2 r13 = h2fma(wxh, D1 - D0, D0);   // {r1(z0,y1), r3(z1,y1)}
        const h2 s01 = h2fma(wyh, r13 - r02, r02);// {s0(z0),    s1(z1)}

        const float s0f = (float)s01.x;
        const float s1f = (float)s01.y;
        return fmaf(wz, s1f - s0f, s0f);
    };

    on[p0] = sample((float)(i0 - 2), (float)(j0 - 2), (float)(l0 - 2));
    if (p1 < KP)
        on[p1] = sample((float)(i1 - 2), (float)(j1 - 2), (float)(l1 - 2));
}

// ---------- Fallback (ws too small): single kernel, f32, one barrier ----------
__global__ __launch_bounds__(512) void fastrot_fb_kernel(
    const float* __restrict__ vol,
    const float* __restrict__ theta_v,
    const float* __restrict__ theta,
    float* __restrict__ out)
{
    __shared__ __align__(16) float pad[8][344];
    __shared__ float sR[8][12];

    const int lane = threadIdx.x & 63;
    const int wv   = threadIdx.x >> 6;
    const long long nb = (long long)blockIdx.x * 8;
    const long long n  = nb + wv;

    float4* p4 = (float4*)(&pad[wv][0]);
    const float4 z4 = make_float4(0.f, 0.f, 0.f, 0.f);
    p4[lane] = z4;
    if (lane < (344 / 4 - 64)) p4[lane + 64] = z4;

    const float* vn = vol + n * (long long)KP;
    const int p0 = lane, p1 = lane + 64;
    const float fv0 = vn[p0];
    const float fv1 = (p1 < KP) ? vn[p1] : 0.0f;

    const int i0 = (p0 * 41) >> 10;
    const int q0 = (p0 * 205) >> 10;
    const int j0 = q0 - i0 * 5;
    const int l0 = p0 - q0 * 5;
    const int i1 = (p1 * 41) >> 10;
    const int q1 = (p1 * 205) >> 10;
    const int j1 = q1 - i1 * 5;
    const int l1 = p1 - q1 * 5;

    pad[wv][i0 * 49 + j0 * 7 + l0 + 57] = fv0;
    if (p1 < KP) pad[wv][i1 * 49 + j1 * 7 + l1 + 57] = fv1;

    if (wv == 0 && lane < 8) {
        const long long m = nb + lane;
        const float ax = theta_v[m * 3 + 0];
        const float ay = theta_v[m * 3 + 1];
        const float az = theta_v[m * 3 + 2];
        const float th = theta[m];
        const float d2  = ax * ax + ay * ay + az * az;
        const float inv = rsqrtf(fmaxf(d2, 1e-24f));
        const float vx = ax * inv, vy = ay * inv, vz = az * inv;
        float s, cth;
        __sincosf(th, &s, &cth);
        const float c = 1.0f - cth;
        float* R = &sR[lane][0];
        R[0] = 1.0f - c * (vy * vy + vz * vz);
        R[1] = -s * vz + c * (vx * vy);
        R[2] =  s * vy + c * (vx * vz);
        R[3] =  s * vz + c * (vx * vy);
        R[4] = 1.0f - c * (vx * vx + vz * vz);
        R[5] = -s * vx + c * (vy * vz);
        R[6] = -s * vy + c * (vx * vz);
        R[7] =  s * vx + c * (vy * vz);
        R[8] = 1.0f - c * (vx * vx + vy * vy);
    }

    __syncthreads();

    const float R00 = sR[wv][0], R01 = sR[wv][1], R02 = sR[wv][2];
    const float R10 = sR[wv][3], R11 = sR[wv][4], R12 = sR[wv][5];
    const float R20 = sR[wv][6], R21 = sR[wv][7], R22 = sR[wv][8];

    const float* pw = &pad[wv][0];
    float* on = out + n * (long long)KP;

    auto sample = [&](float Bi, float Bj, float Bl) -> float {
        float xf = fmaf(Bi, R00, fmaf(Bj, R10, fmaf(Bl, R20, 3.0f)));
        float yf = fmaf(Bi, R01, fmaf(Bj, R11, fmaf(Bl, R21, 3.0f)));
        float zf = fmaf(Bi, R02, fmaf(Bj, R12, fmaf(Bl, R22, 3.0f)));
        xf = fminf(fmaxf(xf, 0.0f), 5.99993896f);
        yf = fminf(fmaxf(yf, 0.0f), 5.99993896f);
        zf = fminf(fmaxf(zf, 0.0f), 5.99993896f);
        const int x0 = (int)xf, y0 = (int)yf, z0 = (int)zf;
        const float wx = __builtin_amdgcn_fractf(xf);
        const float wy = __builtin_amdgcn_fractf(yf);
        const float wz = __builtin_amdgcn_fractf(zf);
        const int ci = z0 * 49 + y0 * 7 + x0;
        const float a00 = pw[ci],      a01 = pw[ci + 1];
        const float a10 = pw[ci + 7],  a11 = pw[ci + 8];
        const float a20 = pw[ci + 49], a21 = pw[ci + 50];
        const float a30 = pw[ci + 56], a31 = pw[ci + 57];
        const float r0 = fmaf(wx, a01 - a00, a00);
        const float r1 = fmaf(wx, a11 - a10, a10);
        const float r2 = fmaf(wx, a21 - a20, a20);
        const float r3 = fmaf(wx, a31 - a30, a30);
        const float s0 = fmaf(wy, r1 - r0, r0);
        const float s1 = fmaf(wy, r3 - r2, r2);
        return fmaf(wz, s1 - s0, s0);
    };

    on[p0] = sample((float)(i0 - 2), (float)(j0 - 2), (float)(l0 - 2));
    if (p1 < KP)
        on[p1] = sample((float)(i1 - 2), (float)(j1 - 2), (float)(l1 - 2));
}

extern "C" void kernel_launch(void* const* d_in, const int* in_sizes, int n_in,
                              void* d_out, int out_size, void* d_ws, size_t ws_size,
                              hipStream_t stream) {
    const float* vol     = (const float*)d_in[0];
    const float* theta_v = (const float*)d_in[1];
    const float* theta   = (const float*)d_in[2];
    float* out           = (float*)d_out;

    const int N = in_sizes[2];          // 262144

    const size_t need = (size_t)N * 12 * sizeof(float);   // 12.6 MB
    if (ws_size >= need) {
        float* Rws = (float*)d_ws;
        rodrigues_kernel<<<(N + 255) / 256, 256, 0, stream>>>(theta_v, theta, Rws, N);
        fastrot_kernel<<<N / FPB, FPB * 64, 0, stream>>>(vol, Rws, out);
    } else {
        fastrot_fb_kernel<<<N / 8, 512, 0, stream>>>(vol, theta_v, theta, out);
    }
}

// Round 9
// 81.374 us; speedup vs baseline: 1.0077x; 1.0077x over previous
//
#include <hip/hip_runtime.h>
#include <math.h>

#define KP    125       // 5*5*5 filter taps
#define VOL7P 344       // 7*7*7 = 343 pair-entries (dwords), rounded to /4
#define FPB   4         // one wave per filter, 4 filters per 256-thread block

typedef _Float16 half_t;
typedef half_t h2 __attribute__((ext_vector_type(2)));
typedef __fp16 fp16x2 __attribute__((ext_vector_type(2)));

static __device__ __forceinline__ h2 h2fma(h2 a, h2 b, h2 c) {
    return __builtin_elementwise_fma(a, b, c);
}
static __device__ __forceinline__ h2 cvt_pk(float a, float b) {
    fp16x2 t = __builtin_amdgcn_cvt_pkrtz(a, b);   // v_cvt_pkrtz_f16_f32
    return __builtin_bit_cast(h2, t);
}

// ---------- Kernel A: per-filter Rodrigues -> Rws[n*12 + 0..8] ----------
__global__ __launch_bounds__(256) void rodrigues_kernel(
    const float* __restrict__ theta_v,  // N*3
    const float* __restrict__ theta,    // N
    float* __restrict__ Rws, int N)
{
    const int n = blockIdx.x * 256 + threadIdx.x;
    if (n >= N) return;
    const float ax = theta_v[n * 3 + 0];
    const float ay = theta_v[n * 3 + 1];
    const float az = theta_v[n * 3 + 2];
    const float th = theta[n];
    const float d2  = ax * ax + ay * ay + az * az;
    const float inv = rsqrtf(fmaxf(d2, 1e-24f));
    const float vx = ax * inv, vy = ay * inv, vz = az * inv;
    float s, cth;
    __sincosf(th, &s, &cth);
    const float c = 1.0f - cth;
    float4 r0, r1, r2;
    r0.x = 1.0f - c * (vy * vy + vz * vz);   // R00
    r0.y = -s * vz + c * (vx * vy);          // R01
    r0.z =  s * vy + c * (vx * vz);          // R02
    r0.w =  s * vz + c * (vx * vy);          // R10
    r1.x = 1.0f - c * (vx * vx + vz * vz);   // R11
    r1.y = -s * vx + c * (vy * vz);          // R12
    r1.z = -s * vy + c * (vx * vz);          // R20
    r1.w =  s * vx + c * (vy * vz);          // R21
    r2.x = 1.0f - c * (vx * vx + vy * vy);   // R22
    r2.y = 0.f; r2.z = 0.f; r2.w = 0.f;
    float4* o = (float4*)(Rws + (long long)n * 12);
    o[0] = r0; o[1] = r1; o[2] = r2;
}

// ---------- Kernel B: barrier-free fp16-pair 7^3 sample kernel ----------
__global__ __launch_bounds__(FPB * 64) void fastrot_kernel(
    const float* __restrict__ vol,      // N*125
    const float* __restrict__ Rws,      // N*12
    float* __restrict__ out)            // N*125
{
    // pad entry (z,y,x) = half2 {F(x), F(x+1)}, x in [0,6], where F is the
    // 7^3 zero-ring frame (data 5^3 at +1 per axis). P(6) never read.
    __shared__ __align__(16) unsigned int pad[FPB][VOL7P];

    const int lane = threadIdx.x & 63;
    const int wvu = __builtin_amdgcn_readfirstlane(threadIdx.x >> 6);
    const int n   = blockIdx.x * FPB + wvu;

    // ---- zero-fill 7^3 pair frame: 86 uint4 per filter ----
    uint4* p4 = (uint4*)(&pad[wvu][0]);
    const uint4 z4 = make_uint4(0u, 0u, 0u, 0u);
    p4[lane] = z4;
    if (lane < (VOL7P / 4 - 64)) p4[lane + 64] = z4;   // 86 total

    // ---- load filter values + x-neighbors (coalesced / L1 hits) ----
    const float* vn = vol + (long long)n * KP;
    const int p0 = lane, p1 = lane + 64;

    const int i0 = (p0 * 41) >> 10;
    const int q0 = (p0 * 205) >> 10;
    const int j0 = q0 - i0 * 5;
    const int l0 = p0 - q0 * 5;
    const int i1 = (p1 * 41) >> 10;
    const int q1 = (p1 * 205) >> 10;
    const int j1 = q1 - i1 * 5;
    const int l1 = p1 - q1 * 5;

    const float fv0 = vn[p0];
    const float fv1 = (p1 < KP) ? vn[p1] : 0.0f;
    const float nx0 = (l0 < 4) ? vn[p0 + 1] : 0.0f;                 // p0+1 <= 64
    const float nx1 = (l1 < 4 && p1 < KP) ? vn[p1 + 1] : 0.0f;      // <= 124

    // ---- R for this wave's filter (wave-uniform scalar loads) ----
    const float* Rp = Rws + (long long)n * 12;
    const float R00 = Rp[0], R01 = Rp[1], R02 = Rp[2];
    const float R10 = Rp[3], R11 = Rp[4], R12 = Rp[5];
    const float R20 = Rp[6], R21 = Rp[7], R22 = Rp[8];

    // ---- scatter pair entries: e = (i+1)*49 + (j+1)*7 + (l+1) ----
    {
        const h2 pk0 = cvt_pk(fv0, nx0);
        const int e0 = i0 * 49 + j0 * 7 + l0 + 57;
        pad[wvu][e0] = __builtin_bit_cast(unsigned int, pk0);
        if (l0 == 0) {   // left-border entry {0, v}
            const h2 pb = cvt_pk(0.0f, fv0);
            pad[wvu][e0 - 1] = __builtin_bit_cast(unsigned int, pb);
        }
        if (p1 < KP) {
            const h2 pk1 = cvt_pk(fv1, nx1);
            const int e1 = i1 * 49 + j1 * 7 + l1 + 57;
            pad[wvu][e1] = __builtin_bit_cast(unsigned int, pk1);
            if (l1 == 0) {
                const h2 pb = cvt_pk(0.0f, fv1);
                pad[wvu][e1 - 1] = __builtin_bit_cast(unsigned int, pb);
            }
        }
    }

    const unsigned int* pwu = &pad[wvu][0];
    float* on = out + (long long)n * KP;

    // frame coord: xf = (gx+1)*2 + 1, folded const = +3. Clamp to [0, 5.99994]
    // == zero-pad sampling in the 7-frame (error <= 1e-4*|v| << threshold).
    auto sample = [&](float Bi, float Bj, float Bl) -> float {
        float xf = fmaf(Bi, R00, fmaf(Bj, R10, fmaf(Bl, R20, 3.0f)));
        float yf = fmaf(Bi, R01, fmaf(Bj, R11, fmaf(Bl, R21, 3.0f)));
        float zf = fmaf(Bi, R02, fmaf(Bj, R12, fmaf(Bl, R22, 3.0f)));
        xf = fminf(fmaxf(xf, 0.0f), 5.99993896f);
        yf = fminf(fmaxf(yf, 0.0f), 5.99993896f);
        zf = fminf(fmaxf(zf, 0.0f), 5.99993896f);
        const int x0 = (int)xf, y0 = (int)yf, z0 = (int)zf;  // trunc==floor (>=0)
        const float wx = __builtin_amdgcn_fractf(xf);
        const float wy = __builtin_amdgcn_fractf(yf);
        const float wz = __builtin_amdgcn_fractf(zf);
        const int ci = z0 * 49 + y0 * 7 + x0;        // in [0, 285]

        // 2x ds_read2_b32: (ci, ci+49) and (ci+7, ci+56)
        const h2 A0 = __builtin_bit_cast(h2, pwu[ci]);        // x-pair @ (y0 ,z0)
        const h2 A1 = __builtin_bit_cast(h2, pwu[ci + 49]);   // x-pair @ (y0 ,z1)
        const h2 B0 = __builtin_bit_cast(h2, pwu[ci + 7]);    // x-pair @ (y1 ,z0)
        const h2 B1 = __builtin_bit_cast(h2, pwu[ci + 56]);   // x-pair @ (y1 ,z1)

        // z-lerp then y-lerp in packed fp16; final x-lerp horizontal in f32.
        const h2 wzh = cvt_pk(wz, wz);
        const h2 wyh = cvt_pk(wy, wy);
        const h2 E = h2fma(wzh, A1 - A0, A0);   // x-pair @ y0
        const h2 F = h2fma(wzh, B1 - B0, B0);   // x-pair @ y1
        const h2 G = h2fma(wyh, F - E, E);      // {g(x0), g(x0+1)}
        const float g0 = (float)G.x;
        const float g1 = (float)G.y;
        return fmaf(wx, g1 - g0, g0);
    };

    on[p0] = sample((float)(i0 - 2), (float)(j0 - 2), (float)(l0 - 2));
    if (p1 < KP)
        on[p1] = sample((float)(i1 - 2), (float)(j1 - 2), (float)(l1 - 2));
}

// ---------- Fallback (ws too small): single kernel, f32, one barrier ----------
__global__ __launch_bounds__(512) void fastrot_fb_kernel(
    const float* __restrict__ vol,
    const float* __restrict__ theta_v,
    const float* __restrict__ theta,
    float* __restrict__ out)
{
    __shared__ __align__(16) float pad[8][344];
    __shared__ float sR[8][12];

    const int lane = threadIdx.x & 63;
    const int wv   = threadIdx.x >> 6;
    const long long nb = (long long)blockIdx.x * 8;
    const long long n  = nb + wv;

    float4* p4 = (float4*)(&pad[wv][0]);
    const float4 z4 = make_float4(0.f, 0.f, 0.f, 0.f);
    p4[lane] = z4;
    if (lane < (344 / 4 - 64)) p4[lane + 64] = z4;

    const float* vn = vol + n * (long long)KP;
    const int p0 = lane, p1 = lane + 64;
    const float fv0 = vn[p0];
    const float fv1 = (p1 < KP) ? vn[p1] : 0.0f;

    const int i0 = (p0 * 41) >> 10;
    const int q0 = (p0 * 205) >> 10;
    const int j0 = q0 - i0 * 5;
    const int l0 = p0 - q0 * 5;
    const int i1 = (p1 * 41) >> 10;
    const int q1 = (p1 * 205) >> 10;
    const int j1 = q1 - i1 * 5;
    const int l1 = p1 - q1 * 5;

    pad[wv][i0 * 49 + j0 * 7 + l0 + 57] = fv0;
    if (p1 < KP) pad[wv][i1 * 49 + j1 * 7 + l1 + 57] = fv1;

    if (wv == 0 && lane < 8) {
        const long long m = nb + lane;
        const float ax = theta_v[m * 3 + 0];
        const float ay = theta_v[m * 3 + 1];
        const float az = theta_v[m * 3 + 2];
        const float th = theta[m];
        const float d2  = ax * ax + ay * ay + az * az;
        const float inv = rsqrtf(fmaxf(d2, 1e-24f));
        const float vx = ax * inv, vy = ay * inv, vz = az * inv;
        float s, cth;
        __sincosf(th, &s, &cth);
        const float c = 1.0f - cth;
        float* R = &sR[lane][0];
        R[0] = 1.0f - c * (vy * vy + vz * vz);
        R[1] = -s * vz + c * (vx * vy);
        R[2] =  s * vy + c * (vx * vz);
        R[3] =  s * vz + c * (vx * vy);
        R[4] = 1.0f - c * (vx * vx + vz * vz);
        R[5] = -s * vx + c * (vy * vz);
        R[6] = -s * vy + c * (vx * vz);
        R[7] =  s * vx + c * (vy * vz);
        R[8] = 1.0f - c * (vx * vx + vy * vy);
    }

    __syncthreads();

    const float R00 = sR[wv][0], R01 = sR[wv][1], R02 = sR[wv][2];
    const float R10 = sR[wv][3], R11 = sR[wv][4], R12 = sR[wv][5];
    const float R20 = sR[wv][6], R21 = sR[wv][7], R22 = sR[wv][8];

    const float* pw = &pad[wv][0];
    float* on = out + n * (long long)KP;

    auto sample = [&](float Bi, float Bj, float Bl) -> float {
        float xf = fmaf(Bi, R00, fmaf(Bj, R10, fmaf(Bl, R20, 3.0f)));
        float yf = fmaf(Bi, R01, fmaf(Bj, R11, fmaf(Bl, R21, 3.0f)));
        float zf = fmaf(Bi, R02, fmaf(Bj, R12, fmaf(Bl, R22, 3.0f)));
        xf = fminf(fmaxf(xf, 0.0f), 5.99993896f);
        yf = fminf(fmaxf(yf, 0.0f), 5.99993896f);
        zf = fminf(fmaxf(zf, 0.0f), 5.99993896f);
        const int x0 = (int)xf, y0 = (int)yf, z0 = (int)zf;
        const float wx = __builtin_amdgcn_fractf(xf);
        const float wy = __builtin_amdgcn_fractf(yf);
        const float wz = __builtin_amdgcn_fractf(zf);
        const int ci = z0 * 49 + y0 * 7 + x0;
        const float a00 = pw[ci],      a01 = pw[ci + 1];
        const float a10 = pw[ci + 7],  a11 = pw[ci + 8];
        const float a20 = pw[ci + 49], a21 = pw[ci + 50];
        const float a30 = pw[ci + 56], a31 = pw[ci + 57];
        const float r0 = fmaf(wx, a01 - a00, a00);
        const float r1 = fmaf(wx, a11 - a10, a10);
        const float r2 = fmaf(wx, a21 - a20, a20);
        const float r3 = fmaf(wx, a31 - a30, a30);
        const float s0 = fmaf(wy, r1 - r0, r0);
        const float s1 = fmaf(wy, r3 - r2, r2);
        return fmaf(wz, s1 - s0, s0);
    };

    on[p0] = sample((float)(i0 - 2), (float)(j0 - 2), (float)(l0 - 2));
    if (p1 < KP)
        on[p1] = sample((float)(i1 - 2), (float)(j1 - 2), (float)(l1 - 2));
}

extern "C" void kernel_launch(void* const* d_in, const int* in_sizes, int n_in,
                              void* d_out, int out_size, void* d_ws, size_t ws_size,
                              hipStream_t stream) {
    const float* vol     = (const float*)d_in[0];
    const float* theta_v = (const float*)d_in[1];
    const float* theta   = (const float*)d_in[2];
    float* out           = (float*)d_out;

    const int N = in_sizes[2];          // 262144

    const size_t need = (size_t)N * 12 * sizeof(float);   // 12.6 MB
    if (ws_size >= need) {
        float* Rws = (float*)d_ws;
        rodrigues_kernel<<<(N + 255) / 256, 256, 0, stream>>>(theta_v, theta, Rws, N);
        fastrot_kernel<<<N / FPB, FPB * 64, 0, stream>>>(vol, Rws, out);
    } else {
        fastrot_fb_kernel<<<N / 8, 512, 0, stream>>>(vol, theta_v, theta, out);
    }
}

// Round 10
// 60.682 us; speedup vs baseline: 1.3513x; 1.3410x over previous
//
#include <hip/hip_runtime.h>
#include <math.h>

#define KP    125       // 5*5*5 filter taps
#define VOL7P 344       // 7*7*7 = 343 pair-entries (dwords), rounded to /4
#define WPB   4         // waves per block
#define NF    4         // filters per wave (sequential, pipelined)

typedef _Float16 half_t;
typedef half_t h2 __attribute__((ext_vector_type(2)));
typedef __fp16 fp16x2 __attribute__((ext_vector_type(2)));

static __device__ __forceinline__ h2 h2fma(h2 a, h2 b, h2 c) {
    return __builtin_elementwise_fma(a, b, c);
}
static __device__ __forceinline__ h2 cvt_pk(float a, float b) {
    fp16x2 t = __builtin_amdgcn_cvt_pkrtz(a, b);   // v_cvt_pkrtz_f16_f32
    return __builtin_bit_cast(h2, t);
}

// ---------- Kernel A: per-filter Rodrigues -> Rws[n*12 + 0..8] ----------
__global__ __launch_bounds__(256) void rodrigues_kernel(
    const float* __restrict__ theta_v,  // N*3
    const float* __restrict__ theta,    // N
    float* __restrict__ Rws, int N)
{
    const int n = blockIdx.x * 256 + threadIdx.x;
    if (n >= N) return;
    const float ax = theta_v[n * 3 + 0];
    const float ay = theta_v[n * 3 + 1];
    const float az = theta_v[n * 3 + 2];
    const float th = theta[n];
    const float d2  = ax * ax + ay * ay + az * az;
    const float inv = rsqrtf(fmaxf(d2, 1e-24f));
    const float vx = ax * inv, vy = ay * inv, vz = az * inv;
    float s, cth;
    __sincosf(th, &s, &cth);
    const float c = 1.0f - cth;
    float4 r0, r1, r2;
    r0.x = 1.0f - c * (vy * vy + vz * vz);   // R00
    r0.y = -s * vz + c * (vx * vy);          // R01
    r0.z =  s * vy + c * (vx * vz);          // R02
    r0.w =  s * vz + c * (vx * vy);          // R10
    r1.x = 1.0f - c * (vx * vx + vz * vz);   // R11
    r1.y = -s * vx + c * (vy * vz);          // R12
    r1.z = -s * vy + c * (vx * vz);          // R20
    r1.w =  s * vx + c * (vy * vz);          // R21
    r2.x = 1.0f - c * (vx * vx + vy * vy);   // R22
    r2.y = 0.f; r2.z = 0.f; r2.w = 0.f;
    float4* o = (float4*)(Rws + (long long)n * 12);
    o[0] = r0; o[1] = r1; o[2] = r2;
}

// ---------- Kernel B: 4-filters-per-wave pipelined sample kernel ----------
__global__ __launch_bounds__(WPB * 64) void fastrot_kernel(
    const float* __restrict__ vol,      // N*125
    const float* __restrict__ Rws,      // N*12
    float* __restrict__ out)            // N*125
{
    // pad entry (z,y,x) = half2 {F(x), F(x+1)}, 7^3 zero-ring frame,
    // data 5^3 at +1 per axis. Double-buffered per wave.
    __shared__ __align__(16) unsigned int pad[WPB][2][VOL7P];

    const int lane = threadIdx.x & 63;
    const int ws   = __builtin_amdgcn_readfirstlane(threadIdx.x >> 6);
    const long long base = ((long long)blockIdx.x * WPB + ws) * NF;

    // ---- zero-fill BOTH frame buffers once (ring stays zero across filters;
    //      scatter rewrites the same 150 interior/border entries each filter) ----
    uint4* b0 = (uint4*)(&pad[ws][0][0]);
    uint4* b1 = (uint4*)(&pad[ws][1][0]);
    const uint4 z4 = make_uint4(0u, 0u, 0u, 0u);
    b0[lane] = z4;
    b1[lane] = z4;
    if (lane < (VOL7P / 4 - 64)) { b0[lane + 64] = z4; b1[lane + 64] = z4; }

    // ---- per-wave-constant decomposition & addresses (amortized over NF) ----
    const int p0 = lane, p1 = lane + 64;
    const int i0 = (p0 * 41) >> 10;
    const int q0 = (p0 * 205) >> 10;
    const int j0 = q0 - i0 * 5;
    const int l0 = p0 - q0 * 5;
    const int i1 = (p1 * 41) >> 10;
    const int q1 = (p1 * 205) >> 10;
    const int j1 = q1 - i1 * 5;
    const int l1 = p1 - q1 * 5;
    const bool has1 = (p1 < KP);          // lane < 61
    const int e0 = i0 * 49 + j0 * 7 + l0 + 57;
    const int e1 = i1 * 49 + j1 * 7 + l1 + 57;
    const float Bi0 = (float)(i0 - 2), Bj0 = (float)(j0 - 2), Bl0 = (float)(l0 - 2);
    const float Bi1 = (float)(i1 - 2), Bj1 = (float)(j1 - 2), Bl1 = (float)(l1 - 2);

    // ---- issue ALL filters' global loads upfront (16 outstanding) ----
    float fv0[NF], fv1[NF], nx0[NF], nx1[NF];
#pragma unroll
    for (int k = 0; k < NF; ++k) {
        const float* vn = vol + (base + k) * KP;
        fv0[k] = vn[p0];
        fv1[k] = has1 ? vn[p1] : 0.0f;
        nx0[k] = (l0 < 4) ? vn[p0 + 1] : 0.0f;
        nx1[k] = (has1 && l1 < 4) ? vn[p1 + 1] : 0.0f;
    }

    // ---- per-filter: scatter into buf[k&1], sample 2 points, store ----
#pragma unroll
    for (int k = 0; k < NF; ++k) {
        unsigned int* buf = &pad[ws][k & 1][0];

        // R (wave-uniform scalar loads)
        const float* Rp = Rws + (base + k) * 12;
        const float R00 = Rp[0], R01 = Rp[1], R02 = Rp[2];
        const float R10 = Rp[3], R11 = Rp[4], R12 = Rp[5];
        const float R20 = Rp[6], R21 = Rp[7], R22 = Rp[8];

        // scatter pair entries
        buf[e0] = __builtin_bit_cast(unsigned int, cvt_pk(fv0[k], nx0[k]));
        if (l0 == 0)
            buf[e0 - 1] = __builtin_bit_cast(unsigned int, cvt_pk(0.0f, fv0[k]));
        if (has1) {
            buf[e1] = __builtin_bit_cast(unsigned int, cvt_pk(fv1[k], nx1[k]));
            if (l1 == 0)
                buf[e1 - 1] = __builtin_bit_cast(unsigned int, cvt_pk(0.0f, fv1[k]));
        }

        float* on = out + (base + k) * KP;

        // frame coord: xf = (gx+1)*2 + 1, folded const = +3. Clamp to
        // [0, 5.99994] == zero-pad sampling (error <= 1e-4*|v| << threshold).
        auto sample = [&](float Bi, float Bj, float Bl) -> float {
            float xf = fmaf(Bi, R00, fmaf(Bj, R10, fmaf(Bl, R20, 3.0f)));
            float yf = fmaf(Bi, R01, fmaf(Bj, R11, fmaf(Bl, R21, 3.0f)));
            float zf = fmaf(Bi, R02, fmaf(Bj, R12, fmaf(Bl, R22, 3.0f)));
            xf = fminf(fmaxf(xf, 0.0f), 5.99993896f);
            yf = fminf(fmaxf(yf, 0.0f), 5.99993896f);
            zf = fminf(fmaxf(zf, 0.0f), 5.99993896f);
            const int x0 = (int)xf, y0 = (int)yf, z0 = (int)zf;
            const float wx = __builtin_amdgcn_fractf(xf);
            const float wy = __builtin_amdgcn_fractf(yf);
            const float wz = __builtin_amdgcn_fractf(zf);
            const int ci = z0 * 49 + y0 * 7 + x0;        // in [0, 285]

            // 2x ds_read2_b32: (ci, ci+49) and (ci+7, ci+56)
            const h2 A0 = __builtin_bit_cast(h2, buf[ci]);        // (y0,z0)
            const h2 A1 = __builtin_bit_cast(h2, buf[ci + 49]);   // (y0,z1)
            const h2 B0 = __builtin_bit_cast(h2, buf[ci + 7]);    // (y1,z0)
            const h2 B1 = __builtin_bit_cast(h2, buf[ci + 56]);   // (y1,z1)

            // z-lerp, y-lerp packed fp16; final x-lerp horizontal in f32
            const h2 wzh = cvt_pk(wz, wz);
            const h2 wyh = cvt_pk(wy, wy);
            const h2 E = h2fma(wzh, A1 - A0, A0);
            const h2 F = h2fma(wzh, B1 - B0, B0);
            const h2 G = h2fma(wyh, F - E, E);
            const float g0 = (float)G.x;
            const float g1 = (float)G.y;
            return fmaf(wx, g1 - g0, g0);
        };

        on[p0] = sample(Bi0, Bj0, Bl0);
        if (has1) on[p1] = sample(Bi1, Bj1, Bl1);
    }
}

// ---------- Fallback (ws too small): single kernel, f32, one barrier ----------
__global__ __launch_bounds__(512) void fastrot_fb_kernel(
    const float* __restrict__ vol,
    const float* __restrict__ theta_v,
    const float* __restrict__ theta,
    float* __restrict__ out)
{
    __shared__ __align__(16) float pad[8][344];
    __shared__ float sR[8][12];

    const int lane = threadIdx.x & 63;
    const int wv   = threadIdx.x >> 6;
    const long long nb = (long long)blockIdx.x * 8;
    const long long n  = nb + wv;

    float4* p4 = (float4*)(&pad[wv][0]);
    const float4 z4 = make_float4(0.f, 0.f, 0.f, 0.f);
    p4[lane] = z4;
    if (lane < (344 / 4 - 64)) p4[lane + 64] = z4;

    const float* vn = vol + n * (long long)KP;
    const int p0 = lane, p1 = lane + 64;
    const float fv0 = vn[p0];
    const float fv1 = (p1 < KP) ? vn[p1] : 0.0f;

    const int i0 = (p0 * 41) >> 10;
    const int q0 = (p0 * 205) >> 10;
    const int j0 = q0 - i0 * 5;
    const int l0 = p0 - q0 * 5;
    const int i1 = (p1 * 41) >> 10;
    const int q1 = (p1 * 205) >> 10;
    const int j1 = q1 - i1 * 5;
    const int l1 = p1 - q1 * 5;

    pad[wv][i0 * 49 + j0 * 7 + l0 + 57] = fv0;
    if (p1 < KP) pad[wv][i1 * 49 + j1 * 7 + l1 + 57] = fv1;

    if (wv == 0 && lane < 8) {
        const long long m = nb + lane;
        const float ax = theta_v[m * 3 + 0];
        const float ay = theta_v[m * 3 + 1];
        const float az = theta_v[m * 3 + 2];
        const float th = theta[m];
        const float d2  = ax * ax + ay * ay + az * az;
        const float inv = rsqrtf(fmaxf(d2, 1e-24f));
        const float vx = ax * inv, vy = ay * inv, vz = az * inv;
        float s, cth;
        __sincosf(th, &s, &cth);
        const float c = 1.0f - cth;
        float* R = &sR[lane][0];
        R[0] = 1.0f - c * (vy * vy + vz * vz);
        R[1] = -s * vz + c * (vx * vy);
        R[2] =  s * vy + c * (vx * vz);
        R[3] =  s * vz + c * (vx * vy);
        R[4] = 1.0f - c * (vx * vx + vz * vz);
        R[5] = -s * vx + c * (vy * vz);
        R[6] = -s * vy + c * (vx * vz);
        R[7] =  s * vx + c * (vy * vz);
        R[8] = 1.0f - c * (vx * vx + vy * vy);
    }

    __syncthreads();

    const float R00 = sR[wv][0], R01 = sR[wv][1], R02 = sR[wv][2];
    const float R10 = sR[wv][3], R11 = sR[wv][4], R12 = sR[wv][5];
    const float R20 = sR[wv][6], R21 = sR[wv][7], R22 = sR[wv][8];

    const float* pw = &pad[wv][0];
    float* on = out + n * (long long)KP;

    auto sample = [&](float Bi, float Bj, float Bl) -> float {
        float xf = fmaf(Bi, R00, fmaf(Bj, R10, fmaf(Bl, R20, 3.0f)));
        float yf = fmaf(Bi, R01, fmaf(Bj, R11, fmaf(Bl, R21, 3.0f)));
        float zf = fmaf(Bi, R02, fmaf(Bj, R12, fmaf(Bl, R22, 3.0f)));
        xf = fminf(fmaxf(xf, 0.0f), 5.99993896f);
        yf = fminf(fmaxf(yf, 0.0f), 5.99993896f);
        zf = fminf(fmaxf(zf, 0.0f), 5.99993896f);
        const int x0 = (int)xf, y0 = (int)yf, z0 = (int)zf;
        const float wx = __builtin_amdgcn_fractf(xf);
        const float wy = __builtin_amdgcn_fractf(yf);
        const float wz = __builtin_amdgcn_fractf(zf);
        const int ci = z0 * 49 + y0 * 7 + x0;
        const float a00 = pw[ci],      a01 = pw[ci + 1];
        const float a10 = pw[ci + 7],  a11 = pw[ci + 8];
        const float a20 = pw[ci + 49], a21 = pw[ci + 50];
        const float a30 = pw[ci + 56], a31 = pw[ci + 57];
        const float r0 = fmaf(wx, a01 - a00, a00);
        const float r1 = fmaf(wx, a11 - a10, a10);
        const float r2 = fmaf(wx, a21 - a20, a20);
        const float r3 = fmaf(wx, a31 - a30, a30);
        const float s0 = fmaf(wy, r1 - r0, r0);
        const float s1 = fmaf(wy, r3 - r2, r2);
        return fmaf(wz, s1 - s0, s0);
    };

    on[p0] = sample((float)(i0 - 2), (float)(j0 - 2), (float)(l0 - 2));
    if (p1 < KP)
        on[p1] = sample((float)(i1 - 2), (float)(j1 - 2), (float)(l1 - 2));
}

extern "C" void kernel_launch(void* const* d_in, const int* in_sizes, int n_in,
                              void* d_out, int out_size, void* d_ws, size_t ws_size,
                              hipStream_t stream) {
    const float* vol     = (const float*)d_in[0];
    const float* theta_v = (const float*)d_in[1];
    const float* theta   = (const float*)d_in[2];
    float* out           = (float*)d_out;

    const int N = in_sizes[2];          // 262144, divisible by WPB*NF = 16

    const size_t need = (size_t)N * 12 * sizeof(float);   // 12.6 MB
    if (ws_size >= need) {
        float* Rws = (float*)d_ws;
        rodrigues_kernel<<<(N + 255) / 256, 256, 0, stream>>>(theta_v, theta, Rws, N);
        fastrot_kernel<<<N / (WPB * NF), WPB * 64, 0, stream>>>(vol, Rws, out);
    } else {
        fastrot_fb_kernel<<<N / 8, 512, 0, stream>>>(vol, theta_v, theta, out);
    }
}